// Round 1
// baseline (85.099 us; speedup 1.0000x reference)
//
#include <hip/hip_runtime.h>
#include <hip/hip_bf16.h>

// Problem constants (reference: Ex/Ey [8192,256] f32, out [8192] f32)
#define NROWS 8192
#define DDIM  256
#define TILE  128
#define ROWB  128      // K bytes per row (fp4: 256 elems * 0.5 B)

typedef int   i32x4  __attribute__((ext_vector_type(4)));
typedef int   i32x8  __attribute__((ext_vector_type(8)));
typedef float f32x4  __attribute__((ext_vector_type(4)));
typedef float f32x16 __attribute__((ext_vector_type(16)));

// exp(LOG_NORM - 0.5*((c-1)/0.05)^2) = exp2(PA*c^2 + PB*c + PC)
#define PA  -288.53900818f
#define PB   577.07801636f
#define PC  -285.54282815f
// exp2f(x) == 0.0f for x <= -160: safe hard-zero skip bound
#define ZCUT -160.0f

// e2m1 code for v (= x*16), RTNE onto {0,.5,1,1.5,2,3,4,6}; bit3 = sign.
__device__ inline unsigned q_e2m1(float v) {
    const float a = __builtin_fabsf(v);
    const unsigned s = (__float_as_uint(v) >> 31) << 3;
    unsigned m;
    if      (a < 0.25f) m = 0;
    else if (a < 0.75f) m = 1;
    else if (a < 1.25f) m = 2;
    else if (a < 1.75f) m = 3;
    else if (a < 2.5f)  m = 4;
    else if (a < 3.5f)  m = 5;
    else if (a < 5.0f)  m = 6;
    else                m = 7;
    return s | m;
}

// Wave-per-row normalize -> unit rows * 16, quantized to fp4 e2m1.
// 1024 blocks x 4 waves x 4 rows = 16384 rows. Blocks 0..7 also zero d_out.
__global__ __launch_bounds__(256) void normalize2(
    const float* __restrict__ Ex, const float* __restrict__ Ey,
    unsigned char* __restrict__ Xn, unsigned char* __restrict__ Yn,
    float* __restrict__ out) {
    const int tid  = threadIdx.x;
    const int wave = tid >> 6;
    const int lane = tid & 63;

    if (blockIdx.x < 8) {                          // zero 8192 floats of out
        f32x4 z = {0.f, 0.f, 0.f, 0.f};
        ((f32x4*)out)[blockIdx.x * 256 + tid] = z;
    }

#pragma unroll
    for (int it = 0; it < 4; ++it) {
        const int gr = blockIdx.x * 16 + wave * 4 + it;   // 0..16383

        const float* src; unsigned char* dst; int row;
        if (gr < NROWS) { src = Ex; dst = Xn; row = gr; }
        else            { src = Ey; dst = Yn; row = gr - NROWS; }

        const float4 v = *(const float4*)(src + (size_t)row * DDIM + lane * 4);
        float ss = v.x * v.x + v.y * v.y + v.z * v.z + v.w * v.w;
#pragma unroll
        for (int o = 32; o > 0; o >>= 1) ss += __shfl_xor(ss, o);
        const float k16 = 16.0f / fmaxf(sqrtf(ss), 1e-8f);  // x*16 for e2m1

        // 4 elems -> 4 nibbles (little-endian: elem lane*4+i -> nibble i)
        unsigned nib =  q_e2m1(v.x * k16)
                     | (q_e2m1(v.y * k16) << 4)
                     | (q_e2m1(v.z * k16) << 8)
                     | (q_e2m1(v.w * k16) << 12);
        const unsigned other = __shfl_xor((int)nib, 1);
        if ((lane & 1) == 0) {                     // even lane stores 4 bytes
            const unsigned word = nib | (other << 16);
            ((unsigned*)(dst + (size_t)row * ROWB))[lane >> 1] = word;
        }
    }
}

__device__ inline void async_load16(const void* g, void* l) {
    __builtin_amdgcn_global_load_lds(
        (const __attribute__((address_space(1))) unsigned int*)g,
        (__attribute__((address_space(3))) unsigned int*)l, 16, 0, 0);
}

// Stage one 128-row fp4 panel (16 KB) into LDS: 4 global_load_lds_dwordx4
// per wave. 16B k-chunks XOR-swizzled by (row&7) on the GLOBAL side, LDS
// dest linear (rule: linear dest + inverse-swz source + swz read).
__device__ inline void stage_panel(const unsigned char* __restrict__ g,
                                   unsigned char* l, int w, int lane) {
    const int lr = lane >> 3;        // row within 8-row group
    const int kc = lane & 7;         // 16B chunk this lane writes
#pragma unroll
    for (int j = 0; j < 4; ++j) {
        const int grp = w * 4 + j;             // 8-row group 0..15
        const int rr  = grp * 8 + lr;
        const int ko  = (kc ^ (rr & 7)) << 4;  // swizzled chunk offset
        async_load16(g + (size_t)rr * ROWB + ko, l + grp * 1024);
    }
}

// C = Xn * Yn^T fused with gaussian + column-sum, MX-FP4.
// Grid (16,64): each block owns one 128-row A panel and walks FOUR 128-col
// B panels (tile cols col0..col0+3).  A panel staged once and its MFMA
// fragments hoisted into registers (8 ds_read_b128 per wave, reused x4).
// B panels double-buffered: stage of panel i+1 issued before compute of i,
// drained by the single end-of-tile __syncthreads.  One barrier per tile,
// no colpart combine: each wave-row atomics its (almost always skipped)
// column sums directly.  4 k-steps of mfma_scale_f32_32x32x64, FMT=4
// (e2m1), scale byte 123 = 2^-4 on both operands (values stored x16).
__global__ __launch_bounds__(256, 3) void cosgauss_gemm(
    const unsigned char* __restrict__ Xn,
    const unsigned char* __restrict__ Yn,
    float* __restrict__ out) {
    __shared__ unsigned char As[TILE * ROWB];      // 16 KB
    __shared__ unsigned char Bs[2][TILE * ROWB];   // 32 KB

    const int tid  = threadIdx.x;
    const int lane = tid & 63;
    const int w    = tid >> 6;       // wave 0..3
    const int wr   = w >> 1;         // wave row 0..1 (64 rows each)
    const int wc   = w & 1;          // wave col 0..1 (64 cols each)
    const int rowBase = blockIdx.y * TILE;
    const int col0    = blockIdx.x * 4;            // first of 4 tile-cols

    stage_panel(Xn + (size_t)rowBase * ROWB, As, w, lane);
    stage_panel(Yn + (size_t)col0 * TILE * ROWB, Bs[0], w, lane);
    __syncthreads();                 // drains vmcnt(0)

    const int r31 = lane & 31;       // mfma: row (A) / col (B) within frag
    const int kh  = lane >> 5;       // mfma: k-half (32 elems = 16 B)
    const int sw  = r31 & 7;         // read-side swizzle key (= row&7)

    // ---- hoist A fragments: 8 ds_read_b128, reused across all 4 tiles
    i32x4 areg[2][4];
#pragma unroll
    for (int rf = 0; rf < 2; ++rf) {
        const unsigned char* p = As + (size_t)(wr * 64 + rf * 32 + r31) * ROWB;
#pragma unroll
        for (int ks = 0; ks < 4; ++ks)
            areg[rf][ks] = *(const i32x4*)(p + (((ks * 2 + kh) ^ sw) << 4));
    }

#pragma unroll
    for (int i = 0; i < 4; ++i) {
        if (i < 3)   // prefetch next B panel into the other buffer
            stage_panel(Yn + (size_t)(col0 + i + 1) * TILE * ROWB,
                        Bs[(i + 1) & 1], w, lane);

        const unsigned char* Bb = Bs[i & 1];
        f32x16 acc[2][2] = {};

        // ---- 4 k-steps of 32x32x64 fp4 (16 MFMA, 8 ds_read_b128 for B)
#pragma unroll
        for (int ks = 0; ks < 4; ++ks) {
            const int co = ((ks * 2 + kh) ^ sw) << 4;
            i32x8 b[2];
#pragma unroll
            for (int cf = 0; cf < 2; ++cf) {
                const unsigned char* p =
                    Bb + (size_t)(wc * 64 + cf * 32 + r31) * ROWB;
                const i32x4 lo = *(const i32x4*)(p + co);
                b[cf][0]=lo[0]; b[cf][1]=lo[1]; b[cf][2]=lo[2]; b[cf][3]=lo[3];
                b[cf][4]=0; b[cf][5]=0; b[cf][6]=0; b[cf][7]=0;
            }
#pragma unroll
            for (int rf = 0; rf < 2; ++rf) {
                i32x8 a;
                a[0]=areg[rf][ks][0]; a[1]=areg[rf][ks][1];
                a[2]=areg[rf][ks][2]; a[3]=areg[rf][ks][3];
                a[4]=0; a[5]=0; a[6]=0; a[7]=0;
#pragma unroll
                for (int cf = 0; cf < 2; ++cf)
                    acc[rf][cf] = __builtin_amdgcn_mfma_scale_f32_32x32x64_f8f6f4(
                        a, b[cf], acc[rf][cf], 4, 4,   // FMT: A=fp4, B=fp4
                        0, 123, 0, 123);               // scales 2^-4
        }
        }

        // ---- epilogue: gaussian + column sums, hard-zero skip (~0.1% pass)
        float cmax = -2.0f;
#pragma unroll
        for (int rf = 0; rf < 2; ++rf)
#pragma unroll
            for (int cf = 0; cf < 2; ++cf)
#pragma unroll
                for (int e = 0; e < 16; ++e)
                    cmax = fmaxf(cmax, acc[rf][cf][e]);
        const bool need = fmaf(cmax, fmaf(cmax, PA, PB), PC) >= ZCUT;

        if (__any(need)) {
            // C/D 32x32 layout: col = lane&31,
            // row = (reg&3)+8*(reg>>2)+4*(lane>>5)  [m74/m101 verified].
            // 16 regs = half the rows; shfl_xor(32) adds the other half.
            const int colBase = (col0 + i) * TILE;
#pragma unroll
            for (int cf = 0; cf < 2; ++cf) {
                float t = 0.0f;
#pragma unroll
                for (int rf = 0; rf < 2; ++rf)
#pragma unroll
                    for (int e = 0; e < 16; ++e) {
                        const float c = acc[rf][cf][e];
                        t += exp2f(fmaf(c, fmaf(c, PA, PB), PC));
                    }
                t += __shfl_xor(t, 32);
                if (lane < 32 && t != 0.0f)
                    atomicAdd(&out[colBase + wc * 64 + cf * 32 + r31], t);
            }
        }
        __syncthreads();   // Bs[(i+1)&1] stage drained; Bs[i&1] reads done
    }
}

extern "C" void kernel_launch(void* const* d_in, const int* in_sizes, int n_in,
                              void* d_out, int out_size, void* d_ws, size_t ws_size,
                              hipStream_t stream) {
    const float* Ex = (const float*)d_in[0];
    const float* Ey = (const float*)d_in[1];
    float* out = (float*)d_out;

    unsigned char* Xn = (unsigned char*)d_ws;                  // 1 MB fp4
    unsigned char* Yn = Xn + (size_t)NROWS * ROWB;             // +1 MB

    normalize2<<<1024, 256, 0, stream>>>(Ex, Ey, Xn, Yn, out);

    dim3 grid(16, NROWS / TILE);     // 16 col-chunks x 64 row panels
    cosgauss_gemm<<<grid, 256, 0, stream>>>(Xn, Yn, out);
}

// Round 2
// 80.099 us; speedup vs baseline: 1.0624x; 1.0624x over previous
//
#include <hip/hip_runtime.h>
#include <hip/hip_bf16.h>

// Problem constants (reference: Ex/Ey [8192,256] f32, out [8192] f32)
#define NROWS 8192
#define DDIM  256
#define TILE  128
#define ROWB  128      // K bytes per row (fp4: 256 elems * 0.5 B)

typedef int   i32x4  __attribute__((ext_vector_type(4)));
typedef int   i32x8  __attribute__((ext_vector_type(8)));
typedef float f32x4  __attribute__((ext_vector_type(4)));
typedef float f32x16 __attribute__((ext_vector_type(16)));

// exp(LOG_NORM - 0.5*((c-1)/0.05)^2) = exp2(PA*c^2 + PB*c + PC)
#define PA  -288.53900818f
#define PB   577.07801636f
#define PC  -285.54282815f
// exp2f(x) == 0.0f for x <= -160: safe hard-zero skip bound
#define ZCUT -160.0f

// e2m1 code for v (= x*16), RTNE onto {0,.5,1,1.5,2,3,4,6}; bit3 = sign.
__device__ inline unsigned q_e2m1(float v) {
    const float a = __builtin_fabsf(v);
    const unsigned s = (__float_as_uint(v) >> 31) << 3;
    unsigned m;
    if      (a < 0.25f) m = 0;
    else if (a < 0.75f) m = 1;
    else if (a < 1.25f) m = 2;
    else if (a < 1.75f) m = 3;
    else if (a < 2.5f)  m = 4;
    else if (a < 3.5f)  m = 5;
    else if (a < 5.0f)  m = 6;
    else                m = 7;
    return s | m;
}

// Wave-per-row normalize -> unit rows * 16, quantized to fp4 e2m1.
// Dequant scale 2^-4 supplied to the MFMA (e8m0 byte 123).
// Blocks 0..7 also zero d_out.  4096 blocks: max dispatch parallelism
// (R1 post-mortem: fewer/fatter blocks lose to scheduling tail).
__global__ __launch_bounds__(256) void normalize2(
    const float* __restrict__ Ex, const float* __restrict__ Ey,
    unsigned char* __restrict__ Xn, unsigned char* __restrict__ Yn,
    float* __restrict__ out) {
    const int tid  = threadIdx.x;
    const int wave = tid >> 6;
    const int lane = tid & 63;
    const int gr   = blockIdx.x * 4 + wave;        // 0..16383

    if (blockIdx.x < 8) {                          // zero 8192 floats of out
        f32x4 z = {0.f, 0.f, 0.f, 0.f};
        ((f32x4*)out)[blockIdx.x * 256 + tid] = z;
    }

    const float* src; unsigned char* dst; int row;
    if (gr < NROWS) { src = Ex; dst = Xn; row = gr; }
    else            { src = Ey; dst = Yn; row = gr - NROWS; }

    const float4 v = *(const float4*)(src + (size_t)row * DDIM + lane * 4);
    float ss = v.x * v.x + v.y * v.y + v.z * v.z + v.w * v.w;
#pragma unroll
    for (int o = 32; o > 0; o >>= 1) ss += __shfl_xor(ss, o);
    const float k16 = 16.0f / fmaxf(sqrtf(ss), 1e-8f);   // x*16 for e2m1 grid

    // 4 elems -> 4 nibbles (little-endian: elem lane*4+i -> nibble i)
    unsigned nib =  q_e2m1(v.x * k16)
                 | (q_e2m1(v.y * k16) << 4)
                 | (q_e2m1(v.z * k16) << 8)
                 | (q_e2m1(v.w * k16) << 12);
    const unsigned other = __shfl_xor((int)nib, 1);
    if ((lane & 1) == 0) {                         // even lane stores 4 bytes
        const unsigned word = nib | (other << 16);
        ((unsigned*)(dst + (size_t)row * ROWB))[lane >> 1] = word;
    }
}

__device__ inline void async_load16(const void* g, void* l) {
    __builtin_amdgcn_global_load_lds(
        (const __attribute__((address_space(1))) unsigned int*)g,
        (__attribute__((address_space(3))) unsigned int*)l, 16, 0, 0);
}

// C = Xn * Yn^T fused with gaussian + column-sum, MX-FP4.
// 128x128 tile, 4 waves 2x2, wave tile 64x64 as 2x2 frags of 32x32.
// fp4 rows are 128 B -> FULL K staged in ONE 32 KB round.  Grid 64x64 =
// 4096 one-tile blocks (measured best: load balance beats traffic
// reduction; panels are L2-resident anyway).  SINGLE barrier per block:
// epilogue atomics directly from both wave-rows (no colpart combine —
// ~97% of waves skip it entirely via the hard-zero gate).
// 4 k-steps of mfma_scale_f32_32x32x64, FMT=4 (e2m1), scale byte 123 =
// 2^-4 on both operands (values stored x16).  Within-chunk nibble/byte
// order cancels between A and B (same packing).  16B k-chunks
// XOR-swizzled by (row&7): zero bank conflicts (measured).
__global__ __launch_bounds__(256, 3) void cosgauss_gemm(
    const unsigned char* __restrict__ Xn,
    const unsigned char* __restrict__ Yn,
    float* __restrict__ out) {
    __shared__ unsigned char As[TILE * ROWB];  // 16 KB
    __shared__ unsigned char Bs[TILE * ROWB];  // 16 KB

    const int tid  = threadIdx.x;
    const int lane = tid & 63;
    const int w    = tid >> 6;       // wave 0..3
    const int wr   = w >> 1;         // wave row 0..1 (64 rows each)
    const int wc   = w & 1;          // wave col 0..1 (64 cols each)
    const int rowBase = blockIdx.y * TILE;
    const int colBase = blockIdx.x * TILE;

    const unsigned char* Ag = Xn + (size_t)rowBase * ROWB;
    const unsigned char* Bg = Yn + (size_t)colBase * ROWB;

    const int lr  = lane >> 3;       // staging: row within 8-row group
    const int kc  = lane & 7;        // staging: 16B chunk this lane writes
    const int r31 = lane & 31;       // mfma: row (A) / col (B) within frag
    const int kh  = lane >> 5;       // mfma: k-half (32 elems = 16 B)
    const int sw  = r31 & 7;         // read-side swizzle key (= row&7)

    // ---- stage full K: 4 instr A + 4 instr B per wave (1 KB = 8 rows each)
#pragma unroll
    for (int j = 0; j < 4; ++j) {
        const int g  = w * 4 + j;              // 8-row group 0..15
        const int rr = g * 8 + lr;
        const int ko = (kc ^ (rr & 7)) << 4;   // swizzled chunk offset
        async_load16(Ag + (size_t)rr * ROWB + ko, (char*)As + g * 1024);
        async_load16(Bg + (size_t)rr * ROWB + ko, (char*)Bs + g * 1024);
    }
    __syncthreads();                 // drains vmcnt(0): the ONLY barrier

    f32x16 acc[2][2] = {};

    // ---- 4 k-steps of 32x32x64 fp4
#pragma unroll
    for (int ks = 0; ks < 4; ++ks) {
        const int c0 = ks * 2 + kh;            // this lane's 16B chunk index
        i32x8 a[2], b[2];
#pragma unroll
        for (int rf = 0; rf < 2; ++rf) {
            const unsigned char* p = As + (wr * 64 + rf * 32 + r31) * ROWB;
            const i32x4 lo = *(const i32x4*)(p + ((c0 ^ sw) << 4));
            a[rf][0]=lo[0]; a[rf][1]=lo[1]; a[rf][2]=lo[2]; a[rf][3]=lo[3];
            a[rf][4]=0; a[rf][5]=0; a[rf][6]=0; a[rf][7]=0;
        }
#pragma unroll
        for (int cf = 0; cf < 2; ++cf) {
            const unsigned char* p = Bs + (wc * 64 + cf * 32 + r31) * ROWB;
            const i32x4 lo = *(const i32x4*)(p + ((c0 ^ sw) << 4));
            b[cf][0]=lo[0]; b[cf][1]=lo[1]; b[cf][2]=lo[2]; b[cf][3]=lo[3];
            b[cf][4]=0; b[cf][5]=0; b[cf][6]=0; b[cf][7]=0;
        }
#pragma unroll
        for (int rf = 0; rf < 2; ++rf)
#pragma unroll
            for (int cf = 0; cf < 2; ++cf)
                acc[rf][cf] = __builtin_amdgcn_mfma_scale_f32_32x32x64_f8f6f4(
                    a[rf], b[cf], acc[rf][cf], 4, 4,   // FMT: A=fp4, B=fp4
                    0, 123, 0, 123);                   // scales 2^-4
    }

    // ---- epilogue: gaussian + column sums, with hard-zero skip.
    float cmax = -2.0f;
#pragma unroll
    for (int rf = 0; rf < 2; ++rf)
#pragma unroll
        for (int cf = 0; cf < 2; ++cf)
#pragma unroll
            for (int e = 0; e < 16; ++e)
                cmax = fmaxf(cmax, acc[rf][cf][e]);
    const bool need = fmaf(cmax, fmaf(cmax, PA, PB), PC) >= ZCUT;

    if (__any(need)) {               // ~3% of waves
        // C/D 32x32 layout: col = lane&31,
        // row = (reg&3)+8*(reg>>2)+4*(lane>>5)  [m74/m101 verified].
        // 16 regs = half of this wave's 64 rows; shfl_xor(32) adds the
        // other half.  Each wave-row contributes its own 64-row partial
        // directly (two atomics/column instead of colpart+barrier).
#pragma unroll
        for (int cf = 0; cf < 2; ++cf) {
            float t = 0.0f;
#pragma unroll
            for (int rf = 0; rf < 2; ++rf)
#pragma unroll
                for (int e = 0; e < 16; ++e) {
                    const float c = acc[rf][cf][e];
                    t += exp2f(fmaf(c, fmaf(c, PA, PB), PC));
                }
            t += __shfl_xor(t, 32);
            if (lane < 32 && t != 0.0f)
                atomicAdd(&out[colBase + wc * 64 + cf * 32 + r31], t);
        }
    }
}

extern "C" void kernel_launch(void* const* d_in, const int* in_sizes, int n_in,
                              void* d_out, int out_size, void* d_ws, size_t ws_size,
                              hipStream_t stream) {
    const float* Ex = (const float*)d_in[0];
    const float* Ey = (const float*)d_in[1];
    float* out = (float*)d_out;

    unsigned char* Xn = (unsigned char*)d_ws;                  // 1 MB fp4
    unsigned char* Yn = Xn + (size_t)NROWS * ROWB;             // +1 MB

    normalize2<<<(2 * NROWS) / 4, 256, 0, stream>>>(Ex, Ey, Xn, Yn, out);

    dim3 grid(NROWS / TILE, NROWS / TILE);   // 64 x 64 one-tile blocks
    cosgauss_gemm<<<grid, 256, 0, stream>>>(Xn, Yn, out);
}